// Round 2
// baseline (489.787 us; speedup 1.0000x reference)
//
#include <hip/hip_runtime.h>
#include <hip/hip_bf16.h>
#include <math.h>

// Problem constants
#define MTOK 16384   // B*N tokens
#define DDIM 1024
#define EEXP 8
#define FDIM 512
#define EFK  4096    // E*F flattened K for second GEMM

typedef __attribute__((ext_vector_type(8))) short short8;   // 8 bf16 = 4 VGPRs (MFMA A/B frag)
typedef __attribute__((ext_vector_type(4))) float floatx4;  // MFMA C/D frag

__device__ __forceinline__ void gld_lds16(const void* g, void* l) {
  // async global->LDS, 16B per lane, dest = wave-uniform base + lane*16
  __builtin_amdgcn_global_load_lds((const __attribute__((address_space(1))) void*)g,
                                   (__attribute__((address_space(3))) void*)l, 16, 0, 0);
}

// Fast exact-GELU via Abramowitz-Stegun 7.1.26 erf approx (|eps| <= 1.5e-7).
__device__ __forceinline__ float gelu_fast(float v) {
  const float z  = v * 0.70710678118654752f;
  const float az = fabsf(z);
  const float t  = __builtin_amdgcn_rcpf(1.f + 0.3275911f * az);
  const float poly = t * (0.254829592f +
                     t * (-0.284496736f +
                     t * (1.421413741f +
                     t * (-1.453152027f +
                     t * 1.061405429f))));
  const float ex = __expf(-az * az);
  float erfv = 1.f - poly * ex;
  erfv = copysignf(erfv, z);
  return 0.5f * v * (1.f + erfv);
}

// ---------------- transpose + fp32->bf16 cast: in [R,C] f32 -> out [C,R] bf16, batched in z
__global__ __launch_bounds__(256) void transpose_cast_kernel(
    const float* __restrict__ in, __hip_bfloat16* __restrict__ out, int R, int C) {
  __shared__ float tile[32][33];
  const float* inb = in + (size_t)blockIdx.z * R * C;
  __hip_bfloat16* outb = out + (size_t)blockIdx.z * R * C;
  const int c0 = blockIdx.x * 32, r0 = blockIdx.y * 32;
  const int tx = threadIdx.x & 31, ty = threadIdx.x >> 5;  // 32 x 8
#pragma unroll
  for (int i = 0; i < 4; ++i)
    tile[ty + i * 8][tx] = inb[(size_t)(r0 + ty + i * 8) * C + (c0 + tx)];
  __syncthreads();
#pragma unroll
  for (int i = 0; i < 4; ++i)
    outb[(size_t)(c0 + ty + i * 8) * R + (r0 + tx)] = __float2bfloat16(tile[tx][ty + i * 8]);
}

// ---------------- router softmax (fp32) + x -> bf16 cast. One wave per token.
__global__ __launch_bounds__(256) void router_cast_kernel(
    const float* __restrict__ x, const float* __restrict__ Wr, const float* __restrict__ br,
    __hip_bfloat16* __restrict__ xbf, float* __restrict__ r) {
  const int wave = (blockIdx.x * 256 + threadIdx.x) >> 6;  // token id
  const int lane = threadIdx.x & 63;
  const float* xr = x + (size_t)wave * DDIM;
  float acc[EEXP];
#pragma unroll
  for (int e = 0; e < EEXP; ++e) acc[e] = 0.f;
#pragma unroll
  for (int i = 0; i < DDIM / 64; ++i) {
    const int d = i * 64 + lane;
    const float xv = xr[d];
    xbf[(size_t)wave * DDIM + d] = __float2bfloat16(xv);
    const float4* w4 = (const float4*)(Wr + (size_t)d * EEXP);
    const float4 w0 = w4[0], w1 = w4[1];
    acc[0] += xv * w0.x; acc[1] += xv * w0.y; acc[2] += xv * w0.z; acc[3] += xv * w0.w;
    acc[4] += xv * w1.x; acc[5] += xv * w1.y; acc[6] += xv * w1.z; acc[7] += xv * w1.w;
  }
#pragma unroll
  for (int off = 32; off; off >>= 1) {
#pragma unroll
    for (int e = 0; e < EEXP; ++e) acc[e] += __shfl_xor(acc[e], off, 64);
  }
  float mx = -1e30f;
#pragma unroll
  for (int e = 0; e < EEXP; ++e) { acc[e] += br[e]; mx = fmaxf(mx, acc[e]); }
  float s = 0.f;
#pragma unroll
  for (int e = 0; e < EEXP; ++e) { acc[e] = expf(acc[e] - mx); s += acc[e]; }
  const float inv = 1.f / s;
  if (lane < EEXP) r[(size_t)wave * EEXP + lane] = acc[lane] * inv;
}

// ============================================================================
// 256x256-tile, BK=64, 8-wave (2 M-halves x 4 N-quarters) GEMM core — m201
// 8-phase ordering: per phase {ds_read quadrant frags; issue stage; [vmcnt(N)];
// s_barrier; lgkmcnt(0); setprio(1); 16 MFMA; setprio(0); s_barrier}.
// ds_reads are issued BEFORE bar1 (drain overlaps previous MFMA tail + barrier
// wait); per-wave lgkmcnt(0) AFTER bar1 staggers MFMA entry -> matrix pipe fed
// while other waves still drain LDS (this ordering was the missing 2x vs the
// reads-after-barrier variant, R1: MfmaUtil 32%).
// bar2 (after MFMA) makes the next phase's stage-write into the buffer that was
// just read safe (all waves' lgkmcnt(0) preceded their MFMA, hence their bar2).
//
// Granules (16 KiB staging units, 2 gld_lds/thread), staged in first-read
// order a0,b0,b1,a1 at phases 0..3 of the PREVIOUS tile. vmcnt FIFO sim
// (steady state, Q entries = granules x2 loads):
//   entry ph0: Q=[b1,a1] done:{a0,b0}; ph0 stages a0' -> Q=[b1,a1,a0'](6),
//     ph1 reads b1 => vmcnt(4) at bar1(ph0).
//   ph1 stages b0' -> Q=[a1,a0',b0'](6), ph2 reads a1 => vmcnt(4).
//   ph2 stages b1' -> Q=[a0',b0',b1'](6), ph3 re-reads b0 (done) => NO WAIT.
//   ph3 stages a1' -> Q=[a0',b0',b1',a1'](8), next-ph0 reads a0',b0' => vmcnt(4).
// Last tile (no staging): entry Q=[b1,a1]; waits vmcnt(2), vmcnt(0), -, -.
// Phase order (0,0),(0,1),(1,1),(1,0) gray-code: reads/phase = 12,4,8,4.
// Swizzle (rule 21): LDS dest linear; per-lane GLOBAL source chunk pre-swizzled
// (chunk = l7 ^ l3) so LDS[row][c] holds G[row][c ^ (row&7)]; reads XOR back.
// ============================================================================
#define BUFSZ 65536
#define AOFF  0
#define BOFF  32768

#define STAGE_A(Q1, QM, K0)                                                        \
  do {                                                                             \
    _Pragma("unroll") for (int r_ = 0; r_ < 2; ++r_) {                             \
      gld_lds16(gA + (size_t)(r_ * 128 + (QM) * 64 + wid * 8 + l3) * LDA_ +        \
                    (K0) + ((l7 ^ l3) * 8),                                        \
                ldsb + (Q1) * BUFSZ + AOFF + (QM) * 16384 +                        \
                    (r_ * 64 + wid * 8) * 128);                                    \
    }                                                                              \
  } while (0)

#define STAGE_B(Q1, QN, K0)                                                        \
  do {                                                                             \
    _Pragma("unroll") for (int r_ = 0; r_ < 2; ++r_) {                             \
      const int lin_ = r_ * 64 + wid * 8 + l3;                                     \
      gld_lds16(gB + (size_t)((lin_ >> 5) * 64 + (QN) * 32 + (lin_ & 31)) * LDB_ + \
                    (K0) + ((l7 ^ l3) * 8),                                        \
                ldsb + (Q1) * BUFSZ + BOFF + (QN) * 16384 +                        \
                    (r_ * 64 + wid * 8) * 128);                                    \
    }                                                                              \
  } while (0)

#define VM4    asm volatile("s_waitcnt vmcnt(4)" ::: "memory")
#define VM2    asm volatile("s_waitcnt vmcnt(2)" ::: "memory")
#define VM0    asm volatile("s_waitcnt vmcnt(0)" ::: "memory")
#define VMNONE ((void)0)

#define PHASE(P, QM, QN, LA, LB, STAGE_STMT, VMWAIT)                               \
  do {                                                                             \
    if (LA) {                                                                      \
      _Pragma("unroll") for (int i_ = 0; i_ < 4; ++i_)                             \
        _Pragma("unroll") for (int k_ = 0; k_ < 2; ++k_)                           \
          af[i_][k_] = *(const short8*)(ldsb + (P) * BUFSZ + AOFF +                \
              (QM) * 16384 + (wr * 64 + i_ * 16 + lanem) * 128 +                   \
              (((k_ * 4 + laneq) ^ swz) * 16));                                    \
    }                                                                              \
    if (LB) {                                                                      \
      _Pragma("unroll") for (int j_ = 0; j_ < 2; ++j_)                             \
        _Pragma("unroll") for (int k_ = 0; k_ < 2; ++k_)                           \
          bf[j_][k_] = *(const short8*)(ldsb + (P) * BUFSZ + BOFF +                \
              (QN) * 16384 + (wc * 32 + j_ * 16 + lanem) * 128 +                   \
              (((k_ * 4 + laneq) ^ swz) * 16));                                    \
    }                                                                              \
    STAGE_STMT;                                                                    \
    __builtin_amdgcn_sched_barrier(0);                                             \
    VMWAIT;                                                                        \
    __builtin_amdgcn_s_barrier();                                                  \
    asm volatile("s_waitcnt lgkmcnt(0)" ::: "memory");                             \
    __builtin_amdgcn_sched_barrier(0);                                             \
    __builtin_amdgcn_s_setprio(1);                                                 \
    _Pragma("unroll") for (int k_ = 0; k_ < 2; ++k_)                               \
      _Pragma("unroll") for (int i_ = 0; i_ < 4; ++i_)                             \
        _Pragma("unroll") for (int j_ = 0; j_ < 2; ++j_)                           \
          acc[(QM) * 4 + i_][(QN) * 2 + j_] =                                      \
              __builtin_amdgcn_mfma_f32_16x16x32_bf16(                             \
                  af[i_][k_], bf[j_][k_], acc[(QM) * 4 + i_][(QN) * 2 + j_],       \
                  0, 0, 0);                                                        \
    __builtin_amdgcn_s_setprio(0);                                                 \
    __builtin_amdgcn_s_barrier();                                                  \
  } while (0)

#define GEMM_CORE(NT)                                                              \
  STAGE_A(0, 0, 0);                                                                \
  STAGE_B(0, 0, 0);                                                                \
  STAGE_B(0, 1, 0);                                                                \
  STAGE_A(0, 1, 0);                                                                \
  VM4;                                                                             \
  __builtin_amdgcn_s_barrier();                                                    \
  for (int kt = 0; kt < (NT) - 1; ++kt) {                                          \
    const int p_ = kt & 1, q_ = p_ ^ 1, k1_ = (kt + 1) * 64;                       \
    PHASE(p_, 0, 0, 1, 1, STAGE_A(q_, 0, k1_), VM4);                               \
    PHASE(p_, 0, 1, 0, 1, STAGE_B(q_, 0, k1_), VM4);                               \
    PHASE(p_, 1, 1, 1, 0, STAGE_B(q_, 1, k1_), VMNONE);                            \
    PHASE(p_, 1, 0, 0, 1, STAGE_A(q_, 1, k1_), VM4);                               \
  }                                                                                \
  {                                                                                \
    const int p_ = ((NT) - 1) & 1;                                                 \
    PHASE(p_, 0, 0, 1, 1, (void)0, VM2);                                           \
    PHASE(p_, 0, 1, 0, 1, (void)0, VM0);                                           \
    PHASE(p_, 1, 1, 1, 0, (void)0, VMNONE);                                        \
    PHASE(p_, 1, 0, 0, 1, (void)0, VMNONE);                                        \
  }

// ---------------- GEMM 1: Hs[tok][e*F+f] = bf16( gelu(x @ W1[e] + b1[e]) * r[tok,e] )
// Grid: 1024 blocks = e(8) x fb(2) x strip(64); strip fastest so the 16 blocks
// sharing a token strip are 64 apart in bid -> same XCD (64%8==0) -> x strip
// L2-resident; each (e,fb) weight slice dispatch-adjacent.
__global__ __launch_bounds__(512, 2) void gemm_h_kernel(
    const __hip_bfloat16* __restrict__ A, const __hip_bfloat16* __restrict__ W1t,
    const float* __restrict__ b1, const float* __restrict__ r,
    __hip_bfloat16* __restrict__ Hs) {
  const int bid = blockIdx.x;
  const int strip = bid & 63, fb = (bid >> 6) & 1, e = bid >> 7;
  const int T0 = strip * 256, F0 = fb * 256;

  __shared__ char ldsb[2 * BUFSZ];   // 128 KiB

  const int tid = threadIdx.x, lane = tid & 63, wid = tid >> 6;
  const int wr = wid >> 2, wc = wid & 3;       // 2 x 4 wave grid
  const int lanem = lane & 15, laneq = lane >> 4;
  const int l3 = lane >> 3, l7 = lane & 7;     // staging lane decompose
  const int swz = lanem & 7;
  const int LDA_ = DDIM, LDB_ = DDIM;

  const __hip_bfloat16* gA = W1t + (size_t)e * FDIM * DDIM + (size_t)F0 * DDIM;
  const __hip_bfloat16* gB = A + (size_t)T0 * DDIM;

  floatx4 acc[8][4];
#pragma unroll
  for (int i = 0; i < 8; ++i)
#pragma unroll
    for (int j = 0; j < 4; ++j) acc[i][j] = (floatx4){0.f, 0.f, 0.f, 0.f};
  short8 af[4][2], bf[2][2];

  GEMM_CORE(DDIM / 64);

  // epilogue: bias -> fast exact-gelu -> router scale -> packed bf16x4 store
#pragma unroll
  for (int nj = 0; nj < 4; ++nj) {
    const int tok = T0 + wc * 64 + nj * 16 + lanem;
    const float rv = r[(size_t)tok * EEXP + e];
#pragma unroll
    for (int mi = 0; mi < 8; ++mi) {
      const int f = F0 + wr * 128 + mi * 16 + laneq * 4;   // 4 consecutive f
      const float4 b4 = *(const float4*)(b1 + e * FDIM + f);
      union { ushort4 u; __hip_bfloat16 h[4]; } pk;
      pk.h[0] = __float2bfloat16(gelu_fast(acc[mi][nj][0] + b4.x) * rv);
      pk.h[1] = __float2bfloat16(gelu_fast(acc[mi][nj][1] + b4.y) * rv);
      pk.h[2] = __float2bfloat16(gelu_fast(acc[mi][nj][2] + b4.z) * rv);
      pk.h[3] = __float2bfloat16(gelu_fast(acc[mi][nj][3] + b4.w) * rv);
      *(ushort4*)(Hs + (size_t)tok * EFK + e * FDIM + f) = pk.u;
    }
  }
}

// ---------------- GEMM 2: out[tok][d] = Hs[tok,:] @ W2flat[:,d] + sum_e r[tok,e]*b2[e,d]
// Grid: 256 blocks; decode puts the 4 d-quarter blocks of one token strip on
// the SAME XCD (bid%8 == strip%8) -> the strip's Hs rows L2-shared 4x.
__global__ __launch_bounds__(512, 2) void gemm_out_kernel(
    const __hip_bfloat16* __restrict__ Hs, const __hip_bfloat16* __restrict__ W2t,
    const float* __restrict__ b2, const float* __restrict__ r,
    float* __restrict__ out) {
  const int bid = blockIdx.x;
  const int strip = (bid >> 5) * 8 + (bid & 7);   // 0..63 token strip
  const int dq = (bid >> 3) & 3;                  // d quarter
  const int T0 = strip * 256, D0 = dq * 256;

  __shared__ char ldsb[2 * BUFSZ];   // 128 KiB

  const int tid = threadIdx.x, lane = tid & 63, wid = tid >> 6;
  const int wr = wid >> 2, wc = wid & 3;
  const int lanem = lane & 15, laneq = lane >> 4;
  const int l3 = lane >> 3, l7 = lane & 7;
  const int swz = lanem & 7;
  const int LDA_ = EFK, LDB_ = EFK;

  const __hip_bfloat16* gA = W2t + (size_t)D0 * EFK;
  const __hip_bfloat16* gB = Hs + (size_t)T0 * EFK;

  floatx4 acc[8][4];
#pragma unroll
  for (int i = 0; i < 8; ++i)
#pragma unroll
    for (int j = 0; j < 4; ++j) acc[i][j] = (floatx4){0.f, 0.f, 0.f, 0.f};
  short8 af[4][2], bf[2][2];

  GEMM_CORE(EFK / 64);

  // epilogue: combined bias sum_e r[tok,e]*b2[e,d], float4 store
#pragma unroll
  for (int mi = 0; mi < 8; ++mi) {
    const int d0 = D0 + wr * 128 + mi * 16 + laneq * 4;    // 4 consecutive d
    float4 b2v[EEXP];
#pragma unroll
    for (int e = 0; e < EEXP; ++e) b2v[e] = *(const float4*)(b2 + e * DDIM + d0);
#pragma unroll
    for (int nj = 0; nj < 4; ++nj) {
      const int tok = T0 + wc * 64 + nj * 16 + lanem;
      const float4* r4 = (const float4*)(r + (size_t)tok * EEXP);
      const float4 r0 = r4[0], r1 = r4[1];
      const float rv[EEXP] = {r0.x, r0.y, r0.z, r0.w, r1.x, r1.y, r1.z, r1.w};
      float bx = 0.f, by = 0.f, bz = 0.f, bw = 0.f;
#pragma unroll
      for (int e = 0; e < EEXP; ++e) {
        bx += rv[e] * b2v[e].x; by += rv[e] * b2v[e].y;
        bz += rv[e] * b2v[e].z; bw += rv[e] * b2v[e].w;
      }
      float4 o;
      o.x = acc[mi][nj][0] + bx; o.y = acc[mi][nj][1] + by;
      o.z = acc[mi][nj][2] + bz; o.w = acc[mi][nj][3] + bw;
      *(float4*)(out + (size_t)tok * DDIM + d0) = o;
    }
  }
}

extern "C" void kernel_launch(void* const* d_in, const int* in_sizes, int n_in,
                              void* d_out, int out_size, void* d_ws, size_t ws_size,
                              hipStream_t stream) {
  const float* x  = (const float*)d_in[0];
  const float* W1 = (const float*)d_in[1];
  const float* b1 = (const float*)d_in[2];
  const float* W2 = (const float*)d_in[3];
  const float* b2 = (const float*)d_in[4];
  const float* Wr = (const float*)d_in[5];
  const float* br = (const float*)d_in[6];
  float* out = (float*)d_out;

  char* ws = (char*)d_ws;
  __hip_bfloat16* xbf = (__hip_bfloat16*)(ws);                            // 32 MB
  __hip_bfloat16* W1t = (__hip_bfloat16*)(ws + (32u << 20));              // 8 MB  [E][F][D]
  __hip_bfloat16* W2t = (__hip_bfloat16*)(ws + (40u << 20));              // 8 MB  [D][E*F]
  float*          r   = (float*)(ws + (48u << 20));                       // 0.5 MB [MTOK][E]
  __hip_bfloat16* Hs  = (__hip_bfloat16*)(ws + (48u << 20) + (1u << 19)); // 128 MB [MTOK][E*F]

  // W1 [E][D][F] -> W1t [E][F][D]
  transpose_cast_kernel<<<dim3(FDIM / 32, DDIM / 32, EEXP), 256, 0, stream>>>(W1, W1t, DDIM, FDIM);
  // W2 [E*F][D] -> W2t [D][E*F]
  transpose_cast_kernel<<<dim3(DDIM / 32, EFK / 32, 1), 256, 0, stream>>>(W2, W2t, EFK, DDIM);
  // router softmax + x cast
  router_cast_kernel<<<MTOK / 4, 256, 0, stream>>>(x, Wr, br, xbf, r);
  // stage 1 grouped GEMM (+gelu, +router scale): 256-f x 256-tok tiles
  gemm_h_kernel<<<dim3((MTOK / 256) * (FDIM / 256) * EEXP), 512, 0, stream>>>(xbf, W1t, b1, r, Hs);
  // stage 2 GEMM (+combined bias): 256-d x 256-tok tiles, XCD-grouped strips
  gemm_out_kernel<<<dim3((MTOK / 256) * (DDIM / 256)), 512, 0, stream>>>(Hs, W2t, b2, r, out);
}

// Round 3
// 470.090 us; speedup vs baseline: 1.0419x; 1.0419x over previous
//
#include <hip/hip_runtime.h>
#include <hip/hip_bf16.h>
#include <math.h>

// Problem constants
#define MTOK 16384   // B*N tokens
#define DDIM 1024
#define EEXP 8
#define FDIM 512
#define EFK  4096    // E*F flattened K for second GEMM

typedef __attribute__((ext_vector_type(8))) short short8;   // 8 bf16 = 4 VGPRs (MFMA A/B frag)
typedef __attribute__((ext_vector_type(4))) float floatx4;  // MFMA C/D frag

__device__ __forceinline__ void gld_lds16(const void* g, void* l) {
  // async global->LDS, 16B per lane, dest = wave-uniform base + lane*16
  __builtin_amdgcn_global_load_lds((const __attribute__((address_space(1))) void*)g,
                                   (__attribute__((address_space(3))) void*)l, 16, 0, 0);
}

// Fast exact-GELU via Abramowitz-Stegun 7.1.26 erf approx (|eps| <= 1.5e-7).
__device__ __forceinline__ float gelu_fast(float v) {
  const float z  = v * 0.70710678118654752f;
  const float az = fabsf(z);
  const float t  = __builtin_amdgcn_rcpf(1.f + 0.3275911f * az);
  const float poly = t * (0.254829592f +
                     t * (-0.284496736f +
                     t * (1.421413741f +
                     t * (-1.453152027f +
                     t * 1.061405429f))));
  const float ex = __expf(-az * az);
  float erfv = 1.f - poly * ex;
  erfv = copysignf(erfv, z);
  return 0.5f * v * (1.f + erfv);
}

// ---------------- transpose + fp32->bf16 cast: in [R,C] f32 -> out [C,R] bf16, batched in z
__global__ __launch_bounds__(256) void transpose_cast_kernel(
    const float* __restrict__ in, __hip_bfloat16* __restrict__ out, int R, int C) {
  __shared__ float tile[32][33];
  const float* inb = in + (size_t)blockIdx.z * R * C;
  __hip_bfloat16* outb = out + (size_t)blockIdx.z * R * C;
  const int c0 = blockIdx.x * 32, r0 = blockIdx.y * 32;
  const int tx = threadIdx.x & 31, ty = threadIdx.x >> 5;  // 32 x 8
#pragma unroll
  for (int i = 0; i < 4; ++i)
    tile[ty + i * 8][tx] = inb[(size_t)(r0 + ty + i * 8) * C + (c0 + tx)];
  __syncthreads();
#pragma unroll
  for (int i = 0; i < 4; ++i)
    outb[(size_t)(c0 + ty + i * 8) * R + (r0 + tx)] = __float2bfloat16(tile[tx][ty + i * 8]);
}

// ---------------- router softmax (fp32) + x -> bf16 cast. One wave per token.
__global__ __launch_bounds__(256) void router_cast_kernel(
    const float* __restrict__ x, const float* __restrict__ Wr, const float* __restrict__ br,
    __hip_bfloat16* __restrict__ xbf, float* __restrict__ r) {
  const int wave = (blockIdx.x * 256 + threadIdx.x) >> 6;  // token id
  const int lane = threadIdx.x & 63;
  const float* xr = x + (size_t)wave * DDIM;
  float acc[EEXP];
#pragma unroll
  for (int e = 0; e < EEXP; ++e) acc[e] = 0.f;
#pragma unroll
  for (int i = 0; i < DDIM / 64; ++i) {
    const int d = i * 64 + lane;
    const float xv = xr[d];
    xbf[(size_t)wave * DDIM + d] = __float2bfloat16(xv);
    const float4* w4 = (const float4*)(Wr + (size_t)d * EEXP);
    const float4 w0 = w4[0], w1 = w4[1];
    acc[0] += xv * w0.x; acc[1] += xv * w0.y; acc[2] += xv * w0.z; acc[3] += xv * w0.w;
    acc[4] += xv * w1.x; acc[5] += xv * w1.y; acc[6] += xv * w1.z; acc[7] += xv * w1.w;
  }
#pragma unroll
  for (int off = 32; off; off >>= 1) {
#pragma unroll
    for (int e = 0; e < EEXP; ++e) acc[e] += __shfl_xor(acc[e], off, 64);
  }
  float mx = -1e30f;
#pragma unroll
  for (int e = 0; e < EEXP; ++e) { acc[e] += br[e]; mx = fmaxf(mx, acc[e]); }
  float s = 0.f;
#pragma unroll
  for (int e = 0; e < EEXP; ++e) { acc[e] = expf(acc[e] - mx); s += acc[e]; }
  const float inv = 1.f / s;
  if (lane < EEXP) r[(size_t)wave * EEXP + lane] = acc[lane] * inv;
}

// ============================================================================
// 256x256-tile, BK=64, 8-wave (2M x 4N) GEMM core, ONE barrier per K-tile.
//
// R2 post-mortem: per-phase {reads; bar; lgkm(0); MFMA; bar} has ZERO pipe
// overlap — LDS serves all 8 waves' bursts round-robin, so every wave's
// lgkm(0) completes ~simultaneously; LDS burst (~2800 cyc/tile) and MFMA
// cluster (~2480 cyc/tile) strictly alternate => ~7000 cyc/tile = the
// measured 31% MfmaUtil. Fix: overlap BY CONSTRUCTION within each wave.
//
// Per K-tile t (buf p = t&1):
//   STAGE all 8 gld_lds of tile t+1 into buf q   (q's readers drained: each
//     wave hit lgkm(0) mid-tile t-1, before the single barrier)
//   issue ALL 24 frag ds_reads from buf p, pinned order A0(8) B0(4) B1(4) A1(8)
//   lgkm(12) -> MFMA Q0 (A0xB0, 16)   // B1+A1 drain UNDER this cluster
//   lgkm(8)  -> MFMA Q1 (A0xB1, 16)   // A1 drains under this one
//   lgkm(0)  -> MFMA Q2 (A1xB1) + Q3 (A1xB0)
//   vmcnt(0) + s_barrier (fused asm, memory clobber — stage loads were issued
//     a full tile (~3000 cyc >> 900 HBM) earlier, so the drain is ~free; the
//     clobber stops next-iter ds_reads hoisting above the barrier)
// Barriers: 8/tile -> 1/tile. lgkm counts assume pinned issue order, enforced
// with sched_barrier(0); compiler's own precise waits backstop correctness.
// Swizzle (rule 21): LDS dest linear; per-lane GLOBAL source chunk pre-swizzled
// (chunk = l7 ^ l3) so LDS[row][c] holds G[row][c ^ (row&7)]; reads XOR back
// (R1 verified: SQ_LDS_BANK_CONFLICT = 0).
// ============================================================================
#define BUFSZ 65536
#define AOFF  0
#define BOFF  32768

#define STAGE_A(Q1, QM, K0)                                                        \
  do {                                                                             \
    _Pragma("unroll") for (int r_ = 0; r_ < 2; ++r_) {                             \
      gld_lds16(gA + (size_t)(r_ * 128 + (QM) * 64 + wid * 8 + l3) * LDA_ +        \
                    (K0) + ((l7 ^ l3) * 8),                                        \
                ldsb + (Q1) * BUFSZ + AOFF + (QM) * 16384 +                        \
                    (r_ * 64 + wid * 8) * 128);                                    \
    }                                                                              \
  } while (0)

#define STAGE_B(Q1, QN, K0)                                                        \
  do {                                                                             \
    _Pragma("unroll") for (int r_ = 0; r_ < 2; ++r_) {                             \
      const int lin_ = r_ * 64 + wid * 8 + l3;                                     \
      gld_lds16(gB + (size_t)((lin_ >> 5) * 64 + (QN) * 32 + (lin_ & 31)) * LDB_ + \
                    (K0) + ((l7 ^ l3) * 8),                                        \
                ldsb + (Q1) * BUFSZ + BOFF + (QN) * 16384 +                        \
                    (r_ * 64 + wid * 8) * 128);                                    \
    }                                                                              \
  } while (0)

#define STAGE_ALL(Q1, K0)                                                          \
  do { STAGE_A(Q1, 0, K0); STAGE_B(Q1, 0, K0); STAGE_B(Q1, 1, K0);                 \
       STAGE_A(Q1, 1, K0); } while (0)

#define READS_A(P, QM)                                                             \
  _Pragma("unroll") for (int i_ = 0; i_ < 4; ++i_)                                 \
    _Pragma("unroll") for (int k_ = 0; k_ < 2; ++k_)                               \
      af[QM][i_][k_] = *(const short8*)(ldsb + (P) * BUFSZ + AOFF +                \
          (QM) * 16384 + (wr * 64 + i_ * 16 + lanem) * 128 +                       \
          (((k_ * 4 + laneq) ^ swz) * 16));

#define READS_B(P)                                                                 \
  _Pragma("unroll") for (int n_ = 0; n_ < 4; ++n_)                                 \
    _Pragma("unroll") for (int k_ = 0; k_ < 2; ++k_)                               \
      bf[n_][k_] = *(const short8*)(ldsb + (P) * BUFSZ + BOFF +                    \
          (n_ >> 1) * 16384 + (wc * 32 + (n_ & 1) * 16 + lanem) * 128 +            \
          (((k_ * 4 + laneq) ^ swz) * 16));

#define MFMA_Q(QM, QN)                                                             \
  _Pragma("unroll") for (int k_ = 0; k_ < 2; ++k_)                                 \
    _Pragma("unroll") for (int i_ = 0; i_ < 4; ++i_)                               \
      _Pragma("unroll") for (int j_ = 0; j_ < 2; ++j_)                             \
        acc[(QM) * 4 + i_][(QN) * 2 + j_] =                                        \
            __builtin_amdgcn_mfma_f32_16x16x32_bf16(                               \
                af[QM][i_][k_], bf[(QN) * 2 + j_][k_],                             \
                acc[(QM) * 4 + i_][(QN) * 2 + j_], 0, 0, 0);

#define LGKM(N)                                                                    \
  asm volatile("s_waitcnt lgkmcnt(" #N ")" ::: "memory");                          \
  __builtin_amdgcn_sched_barrier(0)

#define GEMM_CORE(NT)                                                              \
  STAGE_ALL(0, 0);                                                                 \
  asm volatile("s_waitcnt vmcnt(0)\n\ts_barrier" ::: "memory");                    \
  for (int kt = 0; kt < (NT); ++kt) {                                              \
    const int p_ = kt & 1;                                                         \
    if (kt + 1 < (NT)) STAGE_ALL(p_ ^ 1, (kt + 1) * 64);                           \
    READS_A(p_, 0);                                                                \
    READS_B(p_);                                                                   \
    __builtin_amdgcn_sched_barrier(0);                                             \
    READS_A(p_, 1);                                                                \
    __builtin_amdgcn_sched_barrier(0);                                             \
    LGKM(12);                                                                      \
    __builtin_amdgcn_s_setprio(1);                                                 \
    MFMA_Q(0, 0);                                                                  \
    __builtin_amdgcn_s_setprio(0);                                                 \
    LGKM(8);                                                                       \
    __builtin_amdgcn_s_setprio(1);                                                 \
    MFMA_Q(0, 1);                                                                  \
    __builtin_amdgcn_s_setprio(0);                                                 \
    LGKM(0);                                                                       \
    __builtin_amdgcn_s_setprio(1);                                                 \
    MFMA_Q(1, 1);                                                                  \
    MFMA_Q(1, 0);                                                                  \
    __builtin_amdgcn_s_setprio(0);                                                 \
    asm volatile("s_waitcnt vmcnt(0)\n\ts_barrier" ::: "memory");                  \
  }

// ---------------- GEMM 1: Hs[tok][e*F+f] = bf16( gelu(x @ W1[e] + b1[e]) * r[tok,e] )
// Grid: 1024 blocks = e(8) x fb(2) x strip(64); strip fastest so the 16 blocks
// sharing a token strip are 64 apart in bid -> same XCD (64%8==0) -> x strip
// L2-resident; each (e,fb) weight slice dispatch-adjacent.
__global__ __launch_bounds__(512, 2) void gemm_h_kernel(
    const __hip_bfloat16* __restrict__ A, const __hip_bfloat16* __restrict__ W1t,
    const float* __restrict__ b1, const float* __restrict__ r,
    __hip_bfloat16* __restrict__ Hs) {
  const int bid = blockIdx.x;
  const int strip = bid & 63, fb = (bid >> 6) & 1, e = bid >> 7;
  const int T0 = strip * 256, F0 = fb * 256;

  __shared__ char ldsb[2 * BUFSZ];   // 128 KiB

  const int tid = threadIdx.x, lane = tid & 63, wid = tid >> 6;
  const int wr = wid >> 2, wc = wid & 3;       // 2 x 4 wave grid
  const int lanem = lane & 15, laneq = lane >> 4;
  const int l3 = lane >> 3, l7 = lane & 7;     // staging lane decompose
  const int swz = lanem & 7;
  const int LDA_ = DDIM, LDB_ = DDIM;

  const __hip_bfloat16* gA = W1t + (size_t)e * FDIM * DDIM + (size_t)F0 * DDIM;
  const __hip_bfloat16* gB = A + (size_t)T0 * DDIM;

  floatx4 acc[8][4];
#pragma unroll
  for (int i = 0; i < 8; ++i)
#pragma unroll
    for (int j = 0; j < 4; ++j) acc[i][j] = (floatx4){0.f, 0.f, 0.f, 0.f};
  short8 af[2][4][2], bf[4][2];

  GEMM_CORE(DDIM / 64);

  // epilogue: bias -> fast exact-gelu -> router scale -> packed bf16x4 store
#pragma unroll
  for (int nj = 0; nj < 4; ++nj) {
    const int tok = T0 + wc * 64 + nj * 16 + lanem;
    const float rv = r[(size_t)tok * EEXP + e];
#pragma unroll
    for (int mi = 0; mi < 8; ++mi) {
      const int f = F0 + wr * 128 + mi * 16 + laneq * 4;   // 4 consecutive f
      const float4 b4 = *(const float4*)(b1 + e * FDIM + f);
      union { ushort4 u; __hip_bfloat16 h[4]; } pk;
      pk.h[0] = __float2bfloat16(gelu_fast(acc[mi][nj][0] + b4.x) * rv);
      pk.h[1] = __float2bfloat16(gelu_fast(acc[mi][nj][1] + b4.y) * rv);
      pk.h[2] = __float2bfloat16(gelu_fast(acc[mi][nj][2] + b4.z) * rv);
      pk.h[3] = __float2bfloat16(gelu_fast(acc[mi][nj][3] + b4.w) * rv);
      *(ushort4*)(Hs + (size_t)tok * EFK + e * FDIM + f) = pk.u;
    }
  }
}

// ---------------- GEMM 2: out[tok][d] = Hs[tok,:] @ W2flat[:,d] + sum_e r[tok,e]*b2[e,d]
// Grid: 256 blocks; decode puts the 4 d-quarter blocks of one token strip on
// the SAME XCD (bid%8 == strip%8) -> the strip's Hs rows L2-shared 4x.
__global__ __launch_bounds__(512, 2) void gemm_out_kernel(
    const __hip_bfloat16* __restrict__ Hs, const __hip_bfloat16* __restrict__ W2t,
    const float* __restrict__ b2, const float* __restrict__ r,
    float* __restrict__ out) {
  const int bid = blockIdx.x;
  const int strip = (bid >> 5) * 8 + (bid & 7);   // 0..63 token strip
  const int dq = (bid >> 3) & 3;                  // d quarter
  const int T0 = strip * 256, D0 = dq * 256;

  __shared__ char ldsb[2 * BUFSZ];   // 128 KiB

  const int tid = threadIdx.x, lane = tid & 63, wid = tid >> 6;
  const int wr = wid >> 2, wc = wid & 3;
  const int lanem = lane & 15, laneq = lane >> 4;
  const int l3 = lane >> 3, l7 = lane & 7;
  const int swz = lanem & 7;
  const int LDA_ = EFK, LDB_ = EFK;

  const __hip_bfloat16* gA = W2t + (size_t)D0 * EFK;
  const __hip_bfloat16* gB = Hs + (size_t)T0 * EFK;

  floatx4 acc[8][4];
#pragma unroll
  for (int i = 0; i < 8; ++i)
#pragma unroll
    for (int j = 0; j < 4; ++j) acc[i][j] = (floatx4){0.f, 0.f, 0.f, 0.f};
  short8 af[2][4][2], bf[4][2];

  GEMM_CORE(EFK / 64);

  // epilogue: combined bias sum_e r[tok,e]*b2[e,d], float4 store
#pragma unroll
  for (int mi = 0; mi < 8; ++mi) {
    const int d0 = D0 + wr * 128 + mi * 16 + laneq * 4;    // 4 consecutive d
    float4 b2v[EEXP];
#pragma unroll
    for (int e = 0; e < EEXP; ++e) b2v[e] = *(const float4*)(b2 + e * DDIM + d0);
#pragma unroll
    for (int nj = 0; nj < 4; ++nj) {
      const int tok = T0 + wc * 64 + nj * 16 + lanem;
      const float4* r4 = (const float4*)(r + (size_t)tok * EEXP);
      const float4 r0 = r4[0], r1 = r4[1];
      const float rv[EEXP] = {r0.x, r0.y, r0.z, r0.w, r1.x, r1.y, r1.z, r1.w};
      float bx = 0.f, by = 0.f, bz = 0.f, bw = 0.f;
#pragma unroll
      for (int e = 0; e < EEXP; ++e) {
        bx += rv[e] * b2v[e].x; by += rv[e] * b2v[e].y;
        bz += rv[e] * b2v[e].z; bw += rv[e] * b2v[e].w;
      }
      float4 o;
      o.x = acc[mi][nj][0] + bx; o.y = acc[mi][nj][1] + by;
      o.z = acc[mi][nj][2] + bz; o.w = acc[mi][nj][3] + bw;
      *(float4*)(out + (size_t)tok * DDIM + d0) = o;
    }
  }
}

extern "C" void kernel_launch(void* const* d_in, const int* in_sizes, int n_in,
                              void* d_out, int out_size, void* d_ws, size_t ws_size,
                              hipStream_t stream) {
  const float* x  = (const float*)d_in[0];
  const float* W1 = (const float*)d_in[1];
  const float* b1 = (const float*)d_in[2];
  const float* W2 = (const float*)d_in[3];
  const float* b2 = (const float*)d_in[4];
  const float* Wr = (const float*)d_in[5];
  const float* br = (const float*)d_in[6];
  float* out = (float*)d_out;

  char* ws = (char*)d_ws;
  __hip_bfloat16* xbf = (__hip_bfloat16*)(ws);                            // 32 MB
  __hip_bfloat16* W1t = (__hip_bfloat16*)(ws + (32u << 20));              // 8 MB  [E][F][D]
  __hip_bfloat16* W2t = (__hip_bfloat16*)(ws + (40u << 20));              // 8 MB  [D][E*F]
  float*          r   = (float*)(ws + (48u << 20));                       // 0.5 MB [MTOK][E]
  __hip_bfloat16* Hs  = (__hip_bfloat16*)(ws + (48u << 20) + (1u << 19)); // 128 MB [MTOK][E*F]

  // W1 [E][D][F] -> W1t [E][F][D]
  transpose_cast_kernel<<<dim3(FDIM / 32, DDIM / 32, EEXP), 256, 0, stream>>>(W1, W1t, DDIM, FDIM);
  // W2 [E*F][D] -> W2t [D][E*F]
  transpose_cast_kernel<<<dim3(DDIM / 32, EFK / 32, 1), 256, 0, stream>>>(W2, W2t, EFK, DDIM);
  // router softmax + x cast
  router_cast_kernel<<<MTOK / 4, 256, 0, stream>>>(x, Wr, br, xbf, r);
  // stage 1 grouped GEMM (+gelu, +router scale): 256-f x 256-tok tiles
  gemm_h_kernel<<<dim3((MTOK / 256) * (FDIM / 256) * EEXP), 512, 0, stream>>>(xbf, W1t, b1, r, Hs);
  // stage 2 GEMM (+combined bias): 256-d x 256-tok tiles, XCD-grouped strips
  gemm_out_kernel<<<dim3((MTOK / 256) * (DDIM / 256)), 512, 0, stream>>>(Hs, W2t, b2, r, out);
}